// Round 17
// baseline (206.936 us; speedup 1.0000x reference)
//
#include <hip/hip_runtime.h>
#include <cstdint>

#define R_TOT 16384
#define T_NT  2048
#define DD    128
#define HH    512
#define MC_   20
#define BR    32             // rows per block in k3
#define STEPS 64             // 2048 / 32 cols
#define NBLK  (R_TOT / BR)   // 512

// Output layout (floats)
#define MASK_OFF 0
#define LOGP_OFF 16384
#define WORD_OFF 32768
#define CHAR_OFF 49152
#define EMB_OFF  376832          // 49152 + 16384*20
#define LOSS_OFF 2473984         // 376832 + 16384*128

// ws layout (float slots)
#define X_OFF     0              // x f32 [16384][128]
#define HDN_OFF   2097152        // hdn f32 [16384][512]
#define HDNB_OFF  10485760       // hdn bf16 ushort[16384*512]
#define WT_OFF    14680064       // wtgt f32 [2048][128]
#define WTT4_OFF  14942208       // wtgtT4 ushort[128][8][64][8]  (524288)
#define W2T_OFF   15204352       // W2Tf f32 [2048][512]
#define W2P_OFF   16252928       // W2p ushort[64][16][4][32][8]  (1048576)
#define ENT_OFF   16777216       // 512
#define CNT_OFF   16777728       // 512

typedef __attribute__((ext_vector_type(8))) short short8v;
typedef __attribute__((ext_vector_type(4))) float f32x4;
typedef unsigned short ushort_t;

__device__ __forceinline__ ushort_t f2bf(float f) {
    union { float f; unsigned int u; } v; v.f = f;
    unsigned int r = v.u + 0x7FFFu + ((v.u >> 16) & 1u);
    return (ushort_t)(r >> 16);
}

__device__ __forceinline__ void stage16(const ushort_t* gsrc, ushort_t* ldst) {
    __builtin_amdgcn_global_load_lds(
        (const __attribute__((address_space(1))) unsigned int*)gsrc,
        (__attribute__((address_space(3))) unsigned int*)ldst, 16, 0, 0);
}

// ---------------- K1: gather embeddings ----------------
__global__ __launch_bounds__(256) void k1_gather(
    const int* __restrict__ inp_word, const int* __restrict__ tgt_ids,
    const float* __restrict__ W, float* __restrict__ x, float* __restrict__ wtgt)
{
    int row = blockIdx.x * 2 + (threadIdx.x >> 7);
    int d = threadIdx.x & 127;
    if (row < R_TOT) {
        int wsrc = inp_word[row];
        x[(size_t)row * DD + d] = W[(size_t)wsrc * DD + d];
    } else {
        int rr = row - R_TOT;
        if (rr < T_NT) {
            int wsrc = tgt_ids[rr];
            wtgt[(size_t)rr * DD + d] = W[(size_t)wsrc * DD + d];
        }
    }
}

// ---------------- K1b: wtgt -> wtgtT4 PV B-fragment pack ----------------
// wtgtT4[((js*2+cs)*8+df)*512 + lane*8 + j] =
//   j<4 ? bf16(wtgt[js*32+cs*16+(lane>>4)*4+j][df*16+(lane&15)]) : 0
__global__ __launch_bounds__(256) void k1b_wtgtT4(
    const float* __restrict__ wtgt, ushort_t* __restrict__ wtgtT4)
{
    const int js = blockIdx.x, t = threadIdx.x;
    #pragma unroll
    for (int i = 0; i < 4; ++i) {
        int s = i * 256 + t;
        int cs = s >> 9, rem = s & 511;
        int df = rem >> 6, lane = rem & 63;
        int lrow = lane & 15, kg = lane >> 4;
        ushort_t* dst = wtgtT4 + (size_t)(((js * 2 + cs) * 8 + df) * 512 + lane * 8);
        #pragma unroll
        for (int j = 0; j < 8; ++j) {
            dst[j] = (j < 4)
                ? f2bf(wtgt[(size_t)(js * 32 + cs * 16 + kg * 4 + j) * DD + df * 16 + lrow])
                : (ushort_t)0;
        }
    }
}

// ---------------- K0: W2 [512][2048] -> W2Tf f32 + W2p fragment pack ----------------
// W2p chunk (js,ks): 1024 ushorts, kgrp-major (conflict-free reads):
//   offset (kgrp*32+c)*8+i = bf16(W2[ks*32+kgrp*8+i][js*32+c])
__global__ __launch_bounds__(256) void k0_w2t(
    const float* __restrict__ W2, float* __restrict__ W2Tf, ushort_t* __restrict__ W2p)
{
    __shared__ float tile[32][33];
    const int js = blockIdx.x, ks = blockIdx.y;
    const int cb = js * 32, kb = ks * 32;
    const int lx = threadIdx.x & 31, ly = threadIdx.x >> 5;
    #pragma unroll
    for (int i = 0; i < 32; i += 8)
        tile[ly + i][lx] = W2[(size_t)(kb + ly + i) * T_NT + cb + lx];
    __syncthreads();
    #pragma unroll
    for (int i = 0; i < 32; i += 8) {
        int c = cb + ly + i, k = kb + lx;
        W2Tf[(size_t)c * HH + k] = tile[lx][ly + i];
    }
    if (threadIdx.x < 128) {
        int c = threadIdx.x >> 2, kgrp = threadIdx.x & 3;
        ushort_t* dst = W2p + (size_t)((js * 16 + ks) * 1024 + (kgrp * 32 + c) * 8);
        #pragma unroll
        for (int i = 0; i < 8; ++i)
            dst[i] = f2bf(tile[kgrp * 8 + i][c]);
    }
}

// ---------------- K2: hdn = relu(x @ W1 + b1), fp32 + bf16 outputs ----------------
__global__ __launch_bounds__(256) void k2_hdn(
    const float* __restrict__ x, const float* __restrict__ W1,
    const float* __restrict__ b1, float* __restrict__ hdn, ushort_t* __restrict__ hdnB)
{
    __shared__ float As[16][64];
    __shared__ float Bs[16][64];
    const int t = threadIdx.x;
    const int bm = blockIdx.x * 64;
    const int bn = blockIdx.y * 64;
    const int tx = t & 15, ty = t >> 4;
    float acc[4][4] = {};
    for (int k0 = 0; k0 < DD; k0 += 16) {
        {
            int m = t >> 2, kq = t & 3;
            float4 v = *(const float4*)(x + (size_t)(bm + m) * DD + k0 + kq * 4);
            As[kq * 4 + 0][m] = v.x; As[kq * 4 + 1][m] = v.y;
            As[kq * 4 + 2][m] = v.z; As[kq * 4 + 3][m] = v.w;
        }
        {
            int k = t >> 4, nq = t & 15;
            *(float4*)(&Bs[k][nq * 4]) =
                *(const float4*)(W1 + (size_t)(k0 + k) * HH + bn + nq * 4);
        }
        __syncthreads();
        #pragma unroll
        for (int k = 0; k < 16; ++k) {
            float a[4], b[4];
            #pragma unroll
            for (int i = 0; i < 4; i++) a[i] = As[k][ty * 4 + i];
            #pragma unroll
            for (int j = 0; j < 4; j++) b[j] = Bs[k][tx * 4 + j];
            #pragma unroll
            for (int i = 0; i < 4; i++)
                #pragma unroll
                for (int j = 0; j < 4; j++)
                    acc[i][j] = fmaf(a[i], b[j], acc[i][j]);
        }
        __syncthreads();
    }
    #pragma unroll
    for (int i = 0; i < 4; i++) {
        int m = bm + ty * 4 + i;
        int n = bn + tx * 4;
        float4 v;
        v.x = fmaxf(acc[i][0] + b1[n + 0], 0.f);
        v.y = fmaxf(acc[i][1] + b1[n + 1], 0.f);
        v.z = fmaxf(acc[i][2] + b1[n + 2], 0.f);
        v.w = fmaxf(acc[i][3] + b1[n + 3], 0.f);
        *(float4*)(hdn + (size_t)m * HH + n) = v;
        ushort4 hb;
        hb.x = f2bf(v.x); hb.y = f2bf(v.y); hb.z = f2bf(v.z); hb.w = f2bf(v.w);
        *(ushort4*)(hdnB + (size_t)m * HH + n) = hb;
    }
}

// ---------------- K3: R11 structure + conflict-free W2p reads ----------------
// 512 blocks x 32 rows, 4 waves = 2 Mgrp x 2 Cgrp. Double-buffered W2p staging,
// one barrier/step. S computed as mfma(W2frag, hdnfrag) -> lane holds its own row's
// 4 cols; stats scalar per lane; PV A-operand built in-register (no P LDS).
__global__ __launch_bounds__(256) void k3_fused(
    const ushort_t* __restrict__ hdnB, const float* __restrict__ hdn,
    const ushort_t* __restrict__ W2p, const float* __restrict__ W2Tf,
    const float* __restrict__ b2, const float* __restrict__ gumbel,
    const int* __restrict__ inp_word, const int* __restrict__ keyword_table,
    const int* __restrict__ tgt_ids, const int* __restrict__ lut,
    const float* __restrict__ x, const ushort_t* __restrict__ wtgtT4,
    float* __restrict__ out, float* __restrict__ entP, float* __restrict__ cntP)
{
    __shared__ ushort_t wS[2 * 16384];      // 64 KB double-buffered W2p tiles; scratch later
    __shared__ float statC1[32 * 8];
    __shared__ int   candS[BR * 2];
    __shared__ float invs2S[BR], entS[BR];
    __shared__ int   mskS[BR];

    const int t = threadIdx.x;
    const int wid = t >> 6, lane = t & 63;
    const int Mgrp = wid >> 1, Cgrp = wid & 1;
    const int lrow = lane & 15, kgrp = lane >> 4;
    const int row0 = blockIdx.x * BR;
    const int rowA = row0 + Mgrp * 16 + lrow;

    // ---- hdn fragments (used as MFMA B operand after swap) ----
    short8v av[16];
    #pragma unroll
    for (int ks = 0; ks < 16; ++ks)
        av[ks] = *(const short8v*)(hdnB + (size_t)rowA * HH + ks * 32 + kgrp * 8);

    // ---- W2 A-frag read base: kgrp-major -> 16-lane groups read 256B contiguous ----
    const ushort_t* wb = wS + (kgrp * 32 + Cgrp * 16 + lrow) * 8;

    // ---- per-lane pointers: lane (r=lrow, kgrp) owns cols Cgrp*16+kgrp*4.. of row rowA
    const float* gp = gumbel + (size_t)rowA * T_NT + Cgrp * 16 + kgrp * 4;
    const float* b2p = b2 + Cgrp * 16 + kgrp * 4;
    const ushort_t* vtp = wtgtT4 + (size_t)Cgrp * 4096 + lane * 8;

    // ---- scalar stats (per lane = per row-slice) ----
    float m_ = -1e30f, sE_ = 0.f, sEl_ = 0.f, s2_ = 0.f;
    float a1_ = -1e30f, a2_ = -1e30f;
    int i1_ = 0, i2_ = 0;
    f32x4 accpv[8];
    #pragma unroll
    for (int df = 0; df < 8; ++df) accpv[df] = (f32x4){0.f, 0.f, 0.f, 0.f};

    // ---- prologue: stage tile 0 into buf 0; load step-0 scalars ----
    {
        const ushort_t* src = W2p + t * 8;
        ushort_t* dst = wS + t * 8;
        #pragma unroll
        for (int i = 0; i < 8; ++i) stage16(src + i * 2048, dst + i * 2048);
    }
    float4 g4 = *(const float4*)gp;
    float4 b2v4 = *(const float4*)b2p;
    __syncthreads();   // tile 0 resident

    int c0 = Cgrp * 16 + kgrp * 4;

    for (int s = 0; s < STEPS; ++s) {
        const int buf = s & 1;

        // 1) prefetch next W2p tile into buf^1 (consumed after this step's barrier)
        if (s + 1 < STEPS) {
            const ushort_t* src = W2p + (size_t)(s + 1) * 16384 + t * 8;
            ushort_t* dst = wS + (buf ^ 1) * 16384 + t * 8;
            #pragma unroll
            for (int i = 0; i < 8; ++i) stage16(src + i * 2048, dst + i * 2048);
        }
        // 2) prefetch next-step scalars + this step's PV B-frags
        const int adv = (s + 1 < STEPS) ? 32 : 0;
        float4 gn4 = *(const float4*)(gp + adv);
        float4 b2n4 = *(const float4*)(b2p + adv);
        gp += 32; b2p += 32;
        short8v bvf[8];
        #pragma unroll
        for (int df = 0; df < 8; ++df)
            bvf[df] = *(const short8v*)(vtp + df * 512);
        vtp += 8192;

        // 3) S tile, swapped operands: D = W2frag · hdnfrag -> lane holds S[r][c0..c0+3]
        const ushort_t* wbb = wb + buf * 16384;
        f32x4 ac0 = (f32x4){0.f,0.f,0.f,0.f}, ac1 = ac0, ac2 = ac0, ac3 = ac0;
        #pragma unroll
        for (int ks = 0; ks < 16; ks += 4) {
            ac0 = __builtin_amdgcn_mfma_f32_16x16x32_bf16(*(const short8v*)(wbb + (ks+0)*1024), av[ks+0], ac0, 0, 0, 0);
            ac1 = __builtin_amdgcn_mfma_f32_16x16x32_bf16(*(const short8v*)(wbb + (ks+1)*1024), av[ks+1], ac1, 0, 0, 0);
            ac2 = __builtin_amdgcn_mfma_f32_16x16x32_bf16(*(const short8v*)(wbb + (ks+2)*1024), av[ks+2], ac2, 0, 0, 0);
            ac3 = __builtin_amdgcn_mfma_f32_16x16x32_bf16(*(const short8v*)(wbb + (ks+3)*1024), av[ks+3], ac3, 0, 0, 0);
        }
        f32x4 acc = (ac0 + ac1) + (ac2 + ac3);

        // 4) stats + top2 + in-register P -> pav (lane-local, no LDS)
        short8v pav;
        pav[4] = 0; pav[5] = 0; pav[6] = 0; pav[7] = 0;
        #pragma unroll
        for (int q = 0; q < 4; ++q) {
            float l = acc[q] + b2v4[q];
            m_ = fmaxf(m_, l);
            float e1 = __expf(l);
            sE_ += e1; sEl_ = fmaf(e1, l, sEl_);
            float a = l + g4[q];
            float p = __expf(2.0f * a);
            s2_ += p;
            if (a > a1_) { a2_ = a1_; i2_ = i1_; a1_ = a; i1_ = c0 + q; }
            else if (a > a2_) { a2_ = a; i2_ = c0 + q; }
            pav[q] = (short)f2bf(p);
        }

        // 5) PV: A = pav (P rows, lane-local), B = wtgtT4 frags
        #pragma unroll
        for (int df = 0; df < 8; ++df)
            accpv[df] = __builtin_amdgcn_mfma_f32_16x16x32_bf16(pav, bvf[df], accpv[df], 0, 0, 0);

        g4 = gn4; b2v4 = b2n4; c0 += 32;
        __syncthreads();   // prefetch (issued at step top) landed; buf^1 ready
    }

    // ---- in-wave reduction across kgrp lanes (rows identical per lane&15) ----
    #pragma unroll
    for (int mk = 16; mk < 64; mk <<= 1) {
        m_ = fmaxf(m_, __shfl_xor(m_, mk));
        sE_ += __shfl_xor(sE_, mk);
        sEl_ += __shfl_xor(sEl_, mk);
        s2_ += __shfl_xor(s2_, mk);
        float ob1 = __shfl_xor(a1_, mk); int oj1 = __shfl_xor(i1_, mk);
        float ob2 = __shfl_xor(a2_, mk); int oj2 = __shfl_xor(i2_, mk);
        if (ob1 > a1_ || (ob1 == a1_ && oj1 < i1_)) {
            if (a1_ > ob2 || (a1_ == ob2 && i1_ < oj2)) { a2_ = a1_; i2_ = i1_; }
            else { a2_ = ob2; i2_ = oj2; }
            a1_ = ob1; i1_ = oj1;
        } else {
            if (ob1 > a2_) { a2_ = ob1; i2_ = oj1; }
        }
    }

    // ---- phase 1: Cgrp1 publishes stats + PV partials ----
    if (Cgrp == 1 && lane < 16) {
        float* st = &statC1[(Mgrp * 16 + lane) * 8];
        st[0] = m_; st[1] = sE_; st[2] = sEl_; st[3] = s2_;
        st[4] = a1_; st[5] = __int_as_float(i1_);
        st[6] = a2_; st[7] = __int_as_float(i2_);
    }
    float* scr = (float*)wS;   // scratch: [Mgrp][16 rows][128 d]
    if (Cgrp == 1) {
        #pragma unroll
        for (int df = 0; df < 8; ++df)
            #pragma unroll
            for (int q = 0; q < 4; ++q)
                scr[Mgrp * 2048 + (kgrp * 4 + q) * 128 + df * 16 + lrow] = accpv[df][q];
    }
    __syncthreads();

    // ---- phase 2: Cgrp0 merges ----
    if (Cgrp == 0) {
        if (lane < 16) {
            const float* st = &statC1[(Mgrp * 16 + lane) * 8];
            float bm = st[0], bsE = st[1], bsEl = st[2], bs2 = st[3];
            float ob1 = st[4]; int oj1 = __float_as_int(st[5]);
            float ob2 = st[6]; int oj2 = __float_as_int(st[7]);
            float m = fmaxf(m_, bm);
            float sE = sE_ + bsE, sEl = sEl_ + bsEl, s2 = s2_ + bs2;
            float a1 = a1_, a2 = a2_; int i1 = i1_, i2 = i2_;
            if (ob1 > a1 || (ob1 == a1 && oj1 < i1)) {
                if (a1 > ob2 || (a1 == ob2 && i1 < oj2)) { a2 = a1; i2 = i1; }
                else { a2 = ob2; i2 = oj2; }
                a1 = ob1; i1 = oj1;
            } else {
                if (ob1 > a2) { a2 = ob1; i2 = oj1; }
            }
            int rl = Mgrp * 16 + lane;
            int grow = row0 + rl;
            int w_in = inp_word[grow];
            int msk = keyword_table[w_in] != 0;
            out[MASK_OFF + grow] = msk ? 1.0f : 0.0f;
            out[LOGP_OFF + grow] = msk ? m : 0.0f;
            invs2S[rl] = 1.0f / s2;
            mskS[rl] = msk;
            entS[rl] = msk ? (__logf(sE) - sEl / sE) : 0.0f;
            candS[rl * 2 + 0] = i1;
            candS[rl * 2 + 1] = i2;
        }
        #pragma unroll
        for (int df = 0; df < 8; ++df)
            #pragma unroll
            for (int q = 0; q < 4; ++q)
                accpv[df][q] += scr[Mgrp * 2048 + (kgrp * 4 + q) * 128 + df * 16 + lrow];
    }
    __syncthreads();

    // ---- x_emb store (Cgrp0 waves, full d) ----
    if (Cgrp == 0) {
        #pragma unroll
        for (int df = 0; df < 8; ++df) {
            #pragma unroll
            for (int q = 0; q < 4; ++q) {
                int rl = Mgrp * 16 + kgrp * 4 + q;
                int grow = row0 + rl;
                int d = df * 16 + lrow;
                float val = accpv[df][q] * invs2S[rl];
                if (!mskS[rl]) val = x[(size_t)grow * DD + d];
                out[EMB_OFF + (size_t)grow * DD + d] = val;
            }
        }
    }

    // ---- repair + word/char outputs: wave wid handles rows wid, wid+4, ... ----
    for (int rr = wid; rr < BR; rr += 4) {
        int grow = row0 + rr;
        int i1 = candS[rr * 2 + 0], i2 = candS[rr * 2 + 1];
        const float* hrow = hdn + (size_t)grow * HH;
        float4 h0 = *(const float4*)(hrow + lane * 8);
        float4 h1 = *(const float4*)(hrow + lane * 8 + 4);
        float v1, v2;
        {
            const float* wrow = W2Tf + (size_t)i1 * HH;
            float4 w0 = *(const float4*)(wrow + lane * 8);
            float4 w1 = *(const float4*)(wrow + lane * 8 + 4);
            float sdot = h0.x*w0.x + h0.y*w0.y + h0.z*w0.z + h0.w*w0.w
                       + h1.x*w1.x + h1.y*w1.y + h1.z*w1.z + h1.w*w1.w;
            #pragma unroll
            for (int mk = 1; mk < 64; mk <<= 1) sdot += __shfl_xor(sdot, mk);
            v1 = sdot + b2[i1] + gumbel[(size_t)grow * T_NT + i1];
        }
        {
            const float* wrow = W2Tf + (size_t)i2 * HH;
            float4 w0 = *(const float4*)(wrow + lane * 8);
            float4 w1 = *(const float4*)(wrow + lane * 8 + 4);
            float sdot = h0.x*w0.x + h0.y*w0.y + h0.z*w0.z + h0.w*w0.w
                       + h1.x*w1.x + h1.y*w1.y + h1.z*w1.z + h1.w*w1.w;
            #pragma unroll
            for (int mk = 1; mk < 64; mk <<= 1) sdot += __shfl_xor(sdot, mk);
            v2 = sdot + b2[i2] + gumbel[(size_t)grow * T_NT + i2];
        }
        int ibest = (v2 > v1 || (v2 == v1 && i2 < i1)) ? i2 : i1;
        int w_in = inp_word[grow];
        int msk = mskS[rr];
        int word = msk ? tgt_ids[ibest] : w_in;
        if (lane == 0) out[WORD_OFF + grow] = (float)word;
        if (lane < MC_)
            out[CHAR_OFF + (size_t)grow * MC_ + lane] = (float)lut[(size_t)word * MC_ + lane];
    }

    if (t == 0) {
        float es = 0.f; int cs = 0;
        #pragma unroll
        for (int r = 0; r < BR; r++) { es += entS[r]; cs += mskS[r]; }
        entP[blockIdx.x] = es;
        cntP[blockIdx.x] = (float)cs;
    }
}

// ---------------- K4: final loss reduction ----------------
__global__ __launch_bounds__(256) void k4_loss(
    const float* __restrict__ entP, const float* __restrict__ cntP, float* __restrict__ out)
{
    __shared__ float sE[256], sC[256];
    int t = threadIdx.x;
    float e = 0.f, c = 0.f;
    for (int i = t; i < NBLK; i += 256) { e += entP[i]; c += cntP[i]; }
    sE[t] = e; sC[t] = c;
    __syncthreads();
    for (int s = 128; s > 0; s >>= 1) {
        if (t < s) { sE[t] += sE[t + s]; sC[t] += sC[t + s]; }
        __syncthreads();
    }
    if (t == 0) {
        float ns = fmaxf(sC[0], 1.0f);
        out[LOSS_OFF] = 0.03f * sE[0] / ns;
    }
}

// ---------------- launch ----------------
extern "C" void kernel_launch(void* const* d_in, const int* in_sizes, int n_in,
                              void* d_out, int out_size, void* d_ws, size_t ws_size,
                              hipStream_t stream) {
    const int* inp_word = (const int*)d_in[0];
    const int* keyword_table = (const int*)d_in[3];
    const int* tgt_ids = (const int*)d_in[4];
    const int* lut = (const int*)d_in[5];
    const float* gumbel = (const float*)d_in[6];
    const float* W = (const float*)d_in[7];
    const float* W1 = (const float*)d_in[8];
    const float* b1 = (const float*)d_in[9];
    const float* W2 = (const float*)d_in[10];
    const float* b2 = (const float*)d_in[11];
    float* out = (float*)d_out;

    float* wsf = (float*)d_ws;
    float* x = wsf + X_OFF;
    float* hdn = wsf + HDN_OFF;
    ushort_t* hdnB = (ushort_t*)(wsf + HDNB_OFF);
    float* wtgt = wsf + WT_OFF;
    ushort_t* wtgtT4 = (ushort_t*)(wsf + WTT4_OFF);
    float* W2Tf = wsf + W2T_OFF;
    ushort_t* W2p = (ushort_t*)(wsf + W2P_OFF);
    float* entP = wsf + ENT_OFF;
    float* cntP = wsf + CNT_OFF;

    k1_gather<<<(R_TOT + T_NT) / 2, 256, 0, stream>>>(inp_word, tgt_ids, W, x, wtgt);
    k1b_wtgtT4<<<64, 256, 0, stream>>>(wtgt, wtgtT4);
    k0_w2t<<<dim3(T_NT / 32, HH / 32), 256, 0, stream>>>(W2, W2Tf, W2p);
    k2_hdn<<<dim3(R_TOT / 64, HH / 64), 256, 0, stream>>>(x, W1, b1, hdn, hdnB);
    k3_fused<<<NBLK, 256, 0, stream>>>(hdnB, hdn, W2p, W2Tf, b2, gumbel,
                                       inp_word, keyword_table, tgt_ids, lut,
                                       x, wtgtT4, out, entP, cntP);
    k4_loss<<<1, 256, 0, stream>>>(entP, cntP, out);
}